// Round 7
// baseline (290.443 us; speedup 1.0000x reference)
//
#include <hip/hip_runtime.h>
#include <math.h>

#define C0f        299792458.0f
#define ALPHA_LINf 2.3025850929940458e-4f   // 1e-3 * ln(10)/10

#define NP   4
#define MD   4
#define NC   100
#define NF   104          // NP + NC
#define NT   512          // 8 waves = 2 batches x 4 waves; 1 block/CU -> 16 waves/CU
#define RRSZ 801
#define XROW 80           // dwords per packed-bf16 mode-row (160 bf16 slots >= 128 K-pad)

typedef __attribute__((ext_vector_type(8))) short short8;   // bf16 MFMA A/B frag (4 VGPR)
typedef __attribute__((ext_vector_type(4))) float float4v;  // MFMA C/D frag

// broadcast lane Q of each quad via DPP quad_perm (VALU pipe) — HW-verified rounds 2-6
template <int Q>
__device__ __forceinline__ float qbcast(float v) {
    int r = __builtin_amdgcn_mov_dpp(__float_as_int(v), Q * 0x55, 0xF, 0xF, true);
    return __int_as_float(r);
}

__global__ __launch_bounds__(NT, 4)   // 4 waves/EU -> VGPR cap 128 (kernel uses ~68)
void raman_kernel(const float* __restrict__ x,
                  const float* __restrict__ sig_freq,
                  const float* __restrict__ sig_pow,
                  const float* __restrict__ sig_loss,
                  const float* __restrict__ loss_coef,
                  const float* __restrict__ overlap,
                  const float* __restrict__ raman,
                  const int*   __restrict__ steps_p,
                  const float* __restrict__ length_p,
                  const float* __restrict__ maxf_p,
                  float* __restrict__ out,
                  int L)
{
    __shared__ float rr[RRSZ + 1];                    // Raman LUT (setup only, shared)
    __shared__ float ffs[2][NF];                      // per-half frequencies
    __shared__ __align__(16) unsigned int Xp[2][2][MD * XROW];  // [half][buf] packed-bf16 state

    const int t    = threadIdx.x;
    const int lane = t & 63;
    const int wv   = t >> 6;        // wave id 0..7
    const int half = wv >> 2;       // batch slot within block
    const int w    = wv & 3;        // wave id within batch 0..3
    const int bb   = blockIdx.x * 2 + half;           // batch index
    const int tl   = t & 255;       // thread id within half
    const int g    = lane >> 4;     // lane-group 0..3
    const int c    = lane & 15;     // fragment col index (mode for c<4)
    const int mm   = lane & 3;

    // ---- stage LUT (cooperative) + per-half frequency vector ----
    for (int k = t; k < L && k <= RRSZ; k += NT) rr[k] = raman[k];
    if (tl < NF) ffs[half][tl] = (tl < NP) ? (C0f / x[bb * 20 + tl]) : sig_freq[tl - NP];
    __syncthreads();

    const float* __restrict__ ff = &ffs[half][0];
    const float maxf  = maxf_p[0];
    const float scale = (float)(L - 1) / maxf;

    auto gain_of = [&](float fi, float fj) -> float {
        float fd  = fj - fi;                          // f_j - f_i
        float pos = fabsf(fd) * scale;
        int idx = (int)pos;                           // pos >= 0: trunc == floor
        if (idx > L - 2) idx = L - 2;
        float ww = pos - (float)idx;
        float gg = rr[idx] * (1.0f - ww) + rr[idx + 1] * ww;
        gg = (fd < 0.0f) ? -gg : gg;                  // antisymmetric
        return gg * fmaxf(1.0f, fi / fj);             // photon-number scaling
    };

    // ---- A fragments in registers: gain rows for tiles {w, w+4}, bf16 RTN ----
    // A-frag layout (HW-verified r5): A[m = 16*T + (lane&15)][k = 32*kt + (lane>>4)*8 + jj]
    short8 Ah[2][4];
#pragma unroll
    for (int tt = 0; tt < 2; ++tt) {
        const int Ti = w + 4 * tt;
        const int ia = 16 * Ti + c;
        const float fi = ff[(ia < NF) ? ia : 0];
#pragma unroll
        for (int kt = 0; kt < 4; ++kt) {
#pragma unroll
            for (int jj = 0; jj < 8; ++jj) {
                const int j = 32 * kt + 8 * g + jj;
                float gv = 0.0f;
                if (ia < NF && j < NF) gv = gain_of(fi, ff[j]);
                unsigned int gb = __float_as_uint(gv);
                unsigned int rb = (gb + 0x7FFFu + ((gb >> 16) & 1u)) >> 16;  // RTN-even
                Ah[tt][kt][jj] = (short)rb;
            }
        }
    }

    // overlap row for mode mm (symmetric matrix: row/col equivalent)
    const float Ox = overlap[mm * MD + 0];
    const float Oy = overlap[mm * MD + 1];
    const float Oz = overlap[mm * MD + 2];
    const float Ow = overlap[mm * MD + 3];

    // ---- state in C-layout regs: element (i = 16*T + 4*g + r, m = c), lanes c<4 ----
    float P[2][4], lossv[2][4];
#pragma unroll
    for (int tt = 0; tt < 2; ++tt) {
#pragma unroll
        for (int r = 0; r < 4; ++r) {
            const int i = 16 * (w + 4 * tt) + 4 * g + r;
            float Pv = 0.0f, lv = 0.0f;
            if (c < 4 && i < NF) {
                const int e = 4 * i + c;
                if (i < NP) {
                    float wl = x[bb * 20 + i] * 1e9f;
                    lv = (loss_coef[2] + loss_coef[1] * wl
                          + loss_coef[0] * wl * wl) * ALPHA_LINf;
                    Pv = x[bb * 20 + NP + e];
                } else {
                    lv = sig_loss[e - NP * MD];
                    Pv = sig_pow[e - NP * MD];
                }
            }
            P[tt][r] = Pv;
            lossv[tt][r] = lv;
        }
    }

    const int   nstep = steps_p[0] - 1;
    const float h  = length_p[0] / (float)(steps_p[0] - 1);
    const float hh = 0.5f * h;
    const float h6 = h / 6.0f;

    // one ODE eval: RTN-pack Xs->bf16 pairs->LDS, barrier, ds_read_b128 = B-frags,
    // 4 MFMA per tile, DPP quad overlap mix, k = (R-loss)*Xs
    auto ode_eval = [&](const float (&Xs)[2][4], int buf, float (&kk)[2][4]) {
        unsigned int* xb = &Xp[half][buf][0];
        if (c < 4) {
#pragma unroll
            for (int tt = 0; tt < 2; ++tt) {
                unsigned int r0 = __float_as_uint(Xs[tt][0]) + 0x8000u;  // round-half-up
                unsigned int r1 = __float_as_uint(Xs[tt][1]) + 0x8000u;
                unsigned int r2 = __float_as_uint(Xs[tt][2]) + 0x8000u;
                unsigned int r3 = __float_as_uint(Xs[tt][3]) + 0x8000u;
                unsigned int d0 = __builtin_amdgcn_perm(r1, r0, 0x07060302u); // {r1.hi, r0.hi}
                unsigned int d1 = __builtin_amdgcn_perm(r3, r2, 0x07060302u);
                *(uint2*)(xb + c * XROW + 8 * (w + 4 * tt) + 2 * g) = make_uint2(d0, d1);
            }
        }
        __syncthreads();
        short8 B[4];
#pragma unroll
        for (int kt = 0; kt < 4; ++kt)
            B[kt] = *reinterpret_cast<const short8*>(xb + mm * XROW + 16 * kt + 4 * g);
#pragma unroll
        for (int tt = 0; tt < 2; ++tt) {
            float4v acc = {0.0f, 0.0f, 0.0f, 0.0f};
#pragma unroll
            for (int kt = 0; kt < 4; ++kt)
                acc = __builtin_amdgcn_mfma_f32_16x16x32_bf16(Ah[tt][kt], B[kt], acc, 0, 0, 0);
#pragma unroll
            for (int r = 0; r < 4; ++r) {
                float v  = acc[r];                    // T[i][c] in C-layout
                float s0 = qbcast<0>(v);
                float s1 = qbcast<1>(v);
                float s2 = qbcast<2>(v);
                float s3 = qbcast<3>(v);
                float R  = Ox * s0 + Oy * s1 + Oz * s2 + Ow * s3;
                kk[tt][r] = (R - lossv[tt][r]) * Xs[tt][r];
            }
        }
    };

    for (int s = 0; s < nstep; ++s) {
        float k1[2][4], kc[2][4], Xs[2][4], ka[2][4];
        ode_eval(P, 0, k1);
#pragma unroll
        for (int tt = 0; tt < 2; ++tt)
#pragma unroll
            for (int r = 0; r < 4; ++r) { ka[tt][r] = k1[tt][r]; Xs[tt][r] = P[tt][r] + hh * k1[tt][r]; }
        ode_eval(Xs, 1, kc);
#pragma unroll
        for (int tt = 0; tt < 2; ++tt)
#pragma unroll
            for (int r = 0; r < 4; ++r) { ka[tt][r] += 2.0f * kc[tt][r]; Xs[tt][r] = P[tt][r] + hh * kc[tt][r]; }
        ode_eval(Xs, 0, kc);
#pragma unroll
        for (int tt = 0; tt < 2; ++tt)
#pragma unroll
            for (int r = 0; r < 4; ++r) { ka[tt][r] += 2.0f * kc[tt][r]; Xs[tt][r] = P[tt][r] + h * kc[tt][r]; }
        ode_eval(Xs, 1, kc);
#pragma unroll
        for (int tt = 0; tt < 2; ++tt)
#pragma unroll
            for (int r = 0; r < 4; ++r) P[tt][r] += h6 * (ka[tt][r] + kc[tt][r]);
    }

    // ---- write signal spectrum (B, NC, MD): element (i,m) -> out[4*i+m-16], i>=NP ----
#pragma unroll
    for (int tt = 0; tt < 2; ++tt) {
#pragma unroll
        for (int r = 0; r < 4; ++r) {
            const int i = 16 * (w + 4 * tt) + 4 * g + r;
            if (c < 4 && i >= NP && i < NF)
                out[bb * (NC * MD) + 4 * i + c - NP * MD] = P[tt][r];
        }
    }
}

extern "C" void kernel_launch(void* const* d_in, const int* in_sizes, int n_in,
                              void* d_out, int out_size, void* d_ws, size_t ws_size,
                              hipStream_t stream) {
    const float* x   = (const float*)d_in[0];
    const float* sf  = (const float*)d_in[1];
    const float* sp  = (const float*)d_in[2];
    const float* sl  = (const float*)d_in[3];
    const float* lc  = (const float*)d_in[4];
    const float* ov  = (const float*)d_in[5];
    const float* rrp = (const float*)d_in[6];
    const int*   stp = (const int*)d_in[10];
    const float* len = (const float*)d_in[11];
    const float* mxf = (const float*)d_in[12];

    const int B = in_sizes[0] / (NP * (1 + MD));   // 512
    const int L = in_sizes[6];                     // 801

    raman_kernel<<<dim3(B / 2), dim3(NT), 0, stream>>>(
        x, sf, sp, sl, lc, ov, rrp, stp, len, mxf, (float*)d_out, L);
}

// Round 8
// 260.947 us; speedup vs baseline: 1.1130x; 1.1130x over previous
//
#include <hip/hip_runtime.h>
#include <math.h>

#define C0f        299792458.0f
#define ALPHA_LINf 2.3025850929940458e-4f   // 1e-3 * ln(10)/10

#define NP   4
#define MD   4
#define NC   100
#define NF   104          // NP + NC
#define NT   448          // 7 waves; wave w owns M-tile w (rows 16w..16w+15); 2 blocks/CU
#define RRSZ 801
#define XROW 80           // dwords per packed-bf16 mode-row (160 bf16 slots >= 128 K-pad)

typedef __attribute__((ext_vector_type(8))) short short8;   // bf16 MFMA A/B frag (4 VGPR)
typedef __attribute__((ext_vector_type(4))) float float4v;  // MFMA C/D frag

// broadcast lane Q of each quad via DPP quad_perm (VALU pipe) — HW-verified rounds 2-7
template <int Q>
__device__ __forceinline__ float qbcast(float v) {
    int r = __builtin_amdgcn_mov_dpp(__float_as_int(v), Q * 0x55, 0xF, 0xF, true);
    return __int_as_float(r);
}

__global__ __launch_bounds__(NT, 4)   // 4 waves/EU -> VGPR cap 128 (uses ~56)
void raman_kernel(const float* __restrict__ x,
                  const float* __restrict__ sig_freq,
                  const float* __restrict__ sig_pow,
                  const float* __restrict__ sig_loss,
                  const float* __restrict__ loss_coef,
                  const float* __restrict__ overlap,
                  const float* __restrict__ raman,
                  const int*   __restrict__ steps_p,
                  const float* __restrict__ length_p,
                  const float* __restrict__ maxf_p,
                  float* __restrict__ out,
                  int L)
{
    __shared__ float rr[RRSZ + 1];                    // Raman LUT (setup only)
    __shared__ float ff[NF];                          // frequencies (setup only)
    __shared__ __align__(16) unsigned int Xp[2][MD * XROW];  // packed-bf16 state, dbuf

    const int t    = threadIdx.x;
    const int b    = blockIdx.x;
    const int lane = t & 63;
    const int w    = t >> 6;        // wave id 0..6 == owned M-tile
    const int g    = lane >> 4;     // lane-group 0..3
    const int c    = lane & 15;     // fragment col index (mode for c<4)
    const int mm   = lane & 3;

    // ---- stage LUT + frequencies; zero Xp K-pad (slots >= 112 never rewritten) ----
    for (int k = t; k < L && k <= RRSZ; k += NT) rr[k] = raman[k];
    for (int k = t; k < 2 * MD * XROW; k += NT) ((unsigned int*)Xp)[k] = 0u;
    if (t < NF) ff[t] = (t < NP) ? (C0f / x[b * 20 + t]) : sig_freq[t - NP];
    __syncthreads();

    const float maxf  = maxf_p[0];
    const float scale = (float)(L - 1) / maxf;

    auto gain_of = [&](float fi, float fj) -> float {
        float fd  = fj - fi;                          // f_j - f_i
        float pos = fabsf(fd) * scale;
        int idx = (int)pos;                           // pos >= 0: trunc == floor
        if (idx > L - 2) idx = L - 2;
        float ww = pos - (float)idx;
        float gg = rr[idx] * (1.0f - ww) + rr[idx + 1] * ww;
        gg = (fd < 0.0f) ? -gg : gg;                  // antisymmetric
        return gg * fmaxf(1.0f, fi / fj);             // photon-number scaling
    };

    // ---- A fragments in registers: gain rows for tile w, bf16 RTN ----
    // A-frag layout (HW-verified r5): A[m = 16*w + (lane&15)][k = 32*kt + (lane>>4)*8 + jj]
    short8 Ah[4];
    {
        const int ia = 16 * w + c;
        const float fi = ff[(ia < NF) ? ia : 0];
#pragma unroll
        for (int kt = 0; kt < 4; ++kt) {
#pragma unroll
            for (int jj = 0; jj < 8; ++jj) {
                const int j = 32 * kt + 8 * g + jj;
                float gv = 0.0f;
                if (ia < NF && j < NF) gv = gain_of(fi, ff[j]);
                unsigned int gb = __float_as_uint(gv);
                unsigned int rb = (gb + 0x7FFFu + ((gb >> 16) & 1u)) >> 16;  // RTN-even
                Ah[kt][jj] = (short)rb;
            }
        }
    }

    // overlap row for mode mm (symmetric matrix: row/col equivalent)
    const float Ox = overlap[mm * MD + 0];
    const float Oy = overlap[mm * MD + 1];
    const float Oz = overlap[mm * MD + 2];
    const float Ow = overlap[mm * MD + 3];

    // ---- state in C-layout regs: element (i = 16*w + 4*g + r, m = c), lanes c<4 ----
    float P[4], lossv[4];
#pragma unroll
    for (int r = 0; r < 4; ++r) {
        const int i = 16 * w + 4 * g + r;
        float Pv = 0.0f, lv = 0.0f;
        if (c < 4 && i < NF) {
            const int e = 4 * i + c;
            if (i < NP) {
                float wl = x[b * 20 + i] * 1e9f;
                lv = (loss_coef[2] + loss_coef[1] * wl
                      + loss_coef[0] * wl * wl) * ALPHA_LINf;
                Pv = x[b * 20 + NP + e];
            } else {
                lv = sig_loss[e - NP * MD];
                Pv = sig_pow[e - NP * MD];
            }
        }
        P[r] = Pv;
        lossv[r] = lv;
    }

    const int   nstep = steps_p[0] - 1;
    const float h  = length_p[0] / (float)(steps_p[0] - 1);
    const float hh = 0.5f * h;
    const float h6 = h / 6.0f;

    // one ODE eval: RTN-pack Xs->bf16 pairs->LDS, barrier, ds_read_b128 = B-frags,
    // 4 MFMA, DPP quad overlap mix, k = (R-loss)*Xs
    auto ode_eval = [&](const float (&Xs)[4], int buf, float (&kk)[4]) {
        unsigned int* xb = &Xp[buf][0];
        if (c < 4) {
            unsigned int r0 = __float_as_uint(Xs[0]) + 0x8000u;   // round-half-up
            unsigned int r1 = __float_as_uint(Xs[1]) + 0x8000u;
            unsigned int r2 = __float_as_uint(Xs[2]) + 0x8000u;
            unsigned int r3 = __float_as_uint(Xs[3]) + 0x8000u;
            unsigned int d0 = __builtin_amdgcn_perm(r1, r0, 0x07060302u);  // {r1.hi, r0.hi}
            unsigned int d1 = __builtin_amdgcn_perm(r3, r2, 0x07060302u);
            *(uint2*)(xb + c * XROW + 8 * w + 2 * g) = make_uint2(d0, d1);
        }
        __syncthreads();
        short8 B[4];
#pragma unroll
        for (int kt = 0; kt < 4; ++kt)
            B[kt] = *reinterpret_cast<const short8*>(xb + mm * XROW + 16 * kt + 4 * g);
        float4v acc = {0.0f, 0.0f, 0.0f, 0.0f};
#pragma unroll
        for (int kt = 0; kt < 4; ++kt)
            acc = __builtin_amdgcn_mfma_f32_16x16x32_bf16(Ah[kt], B[kt], acc, 0, 0, 0);
#pragma unroll
        for (int r = 0; r < 4; ++r) {
            float v  = acc[r];                        // T[i][c] in C-layout
            float s0 = qbcast<0>(v);
            float s1 = qbcast<1>(v);
            float s2 = qbcast<2>(v);
            float s3 = qbcast<3>(v);
            float R  = Ox * s0 + Oy * s1 + Oz * s2 + Ow * s3;
            kk[r] = (R - lossv[r]) * Xs[r];
        }
    };

    for (int s = 0; s < nstep; ++s) {
        float k1[4], kc[4], Xs[4], ka[4];
        ode_eval(P, 0, k1);
#pragma unroll
        for (int r = 0; r < 4; ++r) { ka[r] = k1[r]; Xs[r] = P[r] + hh * k1[r]; }
        ode_eval(Xs, 1, kc);
#pragma unroll
        for (int r = 0; r < 4; ++r) { ka[r] += 2.0f * kc[r]; Xs[r] = P[r] + hh * kc[r]; }
        ode_eval(Xs, 0, kc);
#pragma unroll
        for (int r = 0; r < 4; ++r) { ka[r] += 2.0f * kc[r]; Xs[r] = P[r] + h * kc[r]; }
        ode_eval(Xs, 1, kc);
#pragma unroll
        for (int r = 0; r < 4; ++r) P[r] += h6 * (ka[r] + kc[r]);
    }

    // ---- write signal spectrum (B, NC, MD): element (i,m) -> out[4*i+m-16], i>=NP ----
#pragma unroll
    for (int r = 0; r < 4; ++r) {
        const int i = 16 * w + 4 * g + r;
        if (c < 4 && i >= NP && i < NF)
            out[b * (NC * MD) + 4 * i + c - NP * MD] = P[r];
    }
}

extern "C" void kernel_launch(void* const* d_in, const int* in_sizes, int n_in,
                              void* d_out, int out_size, void* d_ws, size_t ws_size,
                              hipStream_t stream) {
    const float* x   = (const float*)d_in[0];
    const float* sf  = (const float*)d_in[1];
    const float* sp  = (const float*)d_in[2];
    const float* sl  = (const float*)d_in[3];
    const float* lc  = (const float*)d_in[4];
    const float* ov  = (const float*)d_in[5];
    const float* rrp = (const float*)d_in[6];
    const int*   stp = (const int*)d_in[10];
    const float* len = (const float*)d_in[11];
    const float* mxf = (const float*)d_in[12];

    const int B = in_sizes[0] / (NP * (1 + MD));   // 512
    const int L = in_sizes[6];                     // 801

    raman_kernel<<<dim3(B), dim3(NT), 0, stream>>>(
        x, sf, sp, sl, lc, ov, rrp, stp, len, mxf, (float*)d_out, L);
}

// Round 9
// 231.871 us; speedup vs baseline: 1.2526x; 1.1254x over previous
//
#include <hip/hip_runtime.h>
#include <math.h>

#define C0f        299792458.0f
#define ALPHA_LINf 2.3025850929940458e-4f   // 1e-3 * ln(10)/10

#define NP   4
#define MD   4
#define NC   100
#define NF   104          // NP + NC
#define NT   448          // 7 waves; wave w owns N-tile w (freqs 16w..16w+15); 2 blocks/CU
#define RRSZ 801
#define AROW 136          // ushorts per A-row (272 B; 68 dwords = 4 mod 32 -> bank-staggered)

typedef __attribute__((ext_vector_type(8))) short short8;   // bf16 MFMA A/B frag (4 VGPR)
typedef __attribute__((ext_vector_type(4))) float float4v;  // MFMA C/D frag

__global__ __launch_bounds__(NT, 4)   // 4 waves/EU -> VGPR cap 128 (uses ~80)
void raman_kernel(const float* __restrict__ x,
                  const float* __restrict__ sig_freq,
                  const float* __restrict__ sig_pow,
                  const float* __restrict__ sig_loss,
                  const float* __restrict__ loss_coef,
                  const float* __restrict__ overlap,
                  const float* __restrict__ raman,
                  const int*   __restrict__ steps_p,
                  const float* __restrict__ length_p,
                  const float* __restrict__ maxf_p,
                  float* __restrict__ out,
                  int L)
{
    __shared__ float rr[RRSZ + 1];                    // Raman LUT (setup only)
    __shared__ float ff[NF];                          // frequencies (setup only)
    // A-operand rows (bf16): row 0 = permanent zeros (feeds A rows 0..3 & 8..15);
    // rows 1..4 = buf0 Y-modes 0..3; rows 5..8 = buf1 Y-modes 0..3.
    __shared__ __align__(16) unsigned short Arows[9 * AROW];

    const int t    = threadIdx.x;
    const int b    = blockIdx.x;
    const int lane = t & 63;
    const int w    = t >> 6;        // wave id 0..6 == owned freq tile (MFMA N-tile)
    const int g    = lane >> 4;     // lane-group 0..3 (K-slice for frags; C-row group)
    const int c    = lane & 15;     // frag row/col index
    const int f    = 16 * w + c;    // global frequency owned by this lane (state on g==1)
    const bool fval = (f < NF);

    // ---- stage LUT + frequencies; zero the A-row region (zero row + pads) ----
    for (int k = t; k < L && k <= RRSZ; k += NT) rr[k] = raman[k];
    for (int k = t; k < 9 * AROW; k += NT) Arows[k] = 0;
    if (t < NF) ff[t] = (t < NP) ? (C0f / x[b * 20 + t]) : sig_freq[t - NP];
    __syncthreads();

    const float maxf  = maxf_p[0];
    const float scale = (float)(L - 1) / maxf;

    auto gain_of = [&](float fi, float fj) -> float {
        float fd  = fj - fi;                          // f_j - f_i
        float pos = fabsf(fd) * scale;
        int idx = (int)pos;                           // pos >= 0: trunc == floor
        if (idx > L - 2) idx = L - 2;
        float ww = pos - (float)idx;
        float gg = rr[idx] * (1.0f - ww) + rr[idx + 1] * ww;
        gg = (fd < 0.0f) ? -gg : gg;                  // antisymmetric
        return gg * fmaxf(1.0f, fi / fj);             // photon-number scaling
    };

    // ---- gain fragments (byte-identical to r5-r8 build), now used as the B operand:
    // per-lane value = gain[16w+c][32kt+8g+jj] == B[k=32kt+8g+jj][n=c] of gain^T ----
    short8 Gf[4];
    {
        const float fi = ff[fval ? f : 0];
#pragma unroll
        for (int kt = 0; kt < 4; ++kt) {
#pragma unroll
            for (int jj = 0; jj < 8; ++jj) {
                const int j = 32 * kt + 8 * g + jj;
                float gv = 0.0f;
                if (fval && j < NF) gv = gain_of(ff[f], ff[j]);
                unsigned int gb = __float_as_uint(gv);
                unsigned int rb = (gb + 0x7FFFu + ((gb >> 16) & 1u)) >> 16;  // RTN-even
                Gf[kt][jj] = (short)rb;
            }
        }
    }

    // ---- full 4x4 overlap matrix per lane (uniform) ----
    float O[MD][MD];
#pragma unroll
    for (int m = 0; m < MD; ++m)
#pragma unroll
        for (int n = 0; n < MD; ++n) O[m][n] = overlap[m * MD + n];

    // ---- state: lane owns modes 0..3 of freq f (valid on g==1; others shadow) ----
    float P[4] = {0, 0, 0, 0}, lossv[4] = {0, 0, 0, 0};
    if (fval) {
        if (f < NP) {
            float wl = x[b * 20 + f] * 1e9f;
            float lv = (loss_coef[2] + loss_coef[1] * wl
                        + loss_coef[0] * wl * wl) * ALPHA_LINf;
#pragma unroll
            for (int r = 0; r < 4; ++r) { lossv[r] = lv; P[r] = x[b * 20 + NP + 4 * f + r]; }
        } else {
            const float4 lo = *(const float4*)&sig_loss[4 * f - NP * MD];
            const float4 pw = *(const float4*)&sig_pow[4 * f - NP * MD];
            lossv[0] = lo.x; lossv[1] = lo.y; lossv[2] = lo.z; lossv[3] = lo.w;
            P[0] = pw.x; P[1] = pw.y; P[2] = pw.z; P[3] = pw.w;
        }
    }

    // per-lane A-frag read base: Y-row (c-4) for c in [4,8), else the shared zero row
    const bool yrow = (c >= 4 && c < 8);
    const unsigned short* pA0 = Arows + (yrow ? (1 + (c - 4)) : 0) * AROW;
    const unsigned short* pA1 = Arows + (yrow ? (5 + (c - 4)) : 0) * AROW;
    const bool writer = (g == 1) && fval;

    const int   nstep = steps_p[0] - 1;
    const float h  = length_p[0] / (float)(steps_p[0] - 1);
    const float hh = 0.5f * h;
    const float h6 = h / 6.0f;

    // one ODE eval: Y = O*Xs (lane-local), RTN-pack Y->mode-rows (b16 scatter),
    // barrier, ds_read_b128 = A-frags, 2x2 MFMA (R lands in rows 4..7 = g==1 lanes),
    // k = (R - loss)*Xs — no cross-lane mix needed.
    auto ode_eval = [&](const float (&Xs)[4], int buf, float (&kk)[4]) {
        float Y[4];
#pragma unroll
        for (int m = 0; m < MD; ++m)
            Y[m] = O[m][0] * Xs[0] + O[m][1] * Xs[1] + O[m][2] * Xs[2] + O[m][3] * Xs[3];
        if (writer) {
            unsigned short* wbase = Arows + (1 + 4 * buf) * AROW + f;
#pragma unroll
            for (int r = 0; r < 4; ++r)
                wbase[r * AROW] = (unsigned short)((__float_as_uint(Y[r]) + 0x8000u) >> 16);
        }
        __syncthreads();
        const unsigned short* pA = buf ? pA1 : pA0;
        short8 A0 = *(const short8*)(pA + 8 * g);
        short8 A1 = *(const short8*)(pA + 32 + 8 * g);
        short8 A2 = *(const short8*)(pA + 64 + 8 * g);
        short8 A3 = *(const short8*)(pA + 96 + 8 * g);
        float4v a01 = {0, 0, 0, 0}, a23 = {0, 0, 0, 0};
        a01 = __builtin_amdgcn_mfma_f32_16x16x32_bf16(A0, Gf[0], a01, 0, 0, 0);
        a01 = __builtin_amdgcn_mfma_f32_16x16x32_bf16(A1, Gf[1], a01, 0, 0, 0);
        a23 = __builtin_amdgcn_mfma_f32_16x16x32_bf16(A2, Gf[2], a23, 0, 0, 0);
        a23 = __builtin_amdgcn_mfma_f32_16x16x32_bf16(A3, Gf[3], a23, 0, 0, 0);
#pragma unroll
        for (int r = 0; r < 4; ++r)
            kk[r] = ((a01[r] + a23[r]) - lossv[r]) * Xs[r];   // R valid on g==1 lanes
    };

    for (int s = 0; s < nstep; ++s) {
        float k1[4], kc[4], Xs[4], ka[4];
        ode_eval(P, 0, k1);
#pragma unroll
        for (int r = 0; r < 4; ++r) { ka[r] = k1[r]; Xs[r] = P[r] + hh * k1[r]; }
        ode_eval(Xs, 1, kc);
#pragma unroll
        for (int r = 0; r < 4; ++r) { ka[r] += 2.0f * kc[r]; Xs[r] = P[r] + hh * kc[r]; }
        ode_eval(Xs, 0, kc);
#pragma unroll
        for (int r = 0; r < 4; ++r) { ka[r] += 2.0f * kc[r]; Xs[r] = P[r] + h * kc[r]; }
        ode_eval(Xs, 1, kc);
#pragma unroll
        for (int r = 0; r < 4; ++r) P[r] += h6 * (ka[r] + kc[r]);
    }

    // ---- write signal spectrum (B, NC, MD): freq f -> out[4f-16 .. 4f-13] ----
    if (writer && f >= NP) {
        float4 o4 = make_float4(P[0], P[1], P[2], P[3]);
        *(float4*)&out[b * (NC * MD) + 4 * f - NP * MD] = o4;
    }
}

extern "C" void kernel_launch(void* const* d_in, const int* in_sizes, int n_in,
                              void* d_out, int out_size, void* d_ws, size_t ws_size,
                              hipStream_t stream) {
    const float* x   = (const float*)d_in[0];
    const float* sf  = (const float*)d_in[1];
    const float* sp  = (const float*)d_in[2];
    const float* sl  = (const float*)d_in[3];
    const float* lc  = (const float*)d_in[4];
    const float* ov  = (const float*)d_in[5];
    const float* rrp = (const float*)d_in[6];
    const int*   stp = (const int*)d_in[10];
    const float* len = (const float*)d_in[11];
    const float* mxf = (const float*)d_in[12];

    const int B = in_sizes[0] / (NP * (1 + MD));   // 512
    const int L = in_sizes[6];                     // 801

    raman_kernel<<<dim3(B), dim3(NT), 0, stream>>>(
        x, sf, sp, sl, lc, ov, rrp, stp, len, mxf, (float*)d_out, L);
}

// Round 10
// 231.809 us; speedup vs baseline: 1.2529x; 1.0003x over previous
//
#include <hip/hip_runtime.h>
#include <math.h>

#define C0f        299792458.0f
#define ALPHA_LINf 2.3025850929940458e-4f   // 1e-3 * ln(10)/10

#define NP   4
#define MD   4
#define NC   100
#define NF   104          // NP + NC
#define NT   448          // 7 waves; wave w owns N-tile w (freqs 16w..16w+15); 2 blocks/CU
#define RRSZ 801
#define AROW 136          // ushorts per Y-row (272 B; 68 dwords = 4 mod 32 -> bank-staggered)

typedef __attribute__((ext_vector_type(8))) short short8;   // bf16 MFMA A/B frag (4 VGPR)
typedef __attribute__((ext_vector_type(4))) float float4v;  // MFMA C/D frag

__global__ __launch_bounds__(NT, 4)   // 4 waves/EU -> VGPR cap 128 (uses ~80)
void raman_kernel(const float* __restrict__ x,
                  const float* __restrict__ sig_freq,
                  const float* __restrict__ sig_pow,
                  const float* __restrict__ sig_loss,
                  const float* __restrict__ loss_coef,
                  const float* __restrict__ overlap,
                  const float* __restrict__ raman,
                  const int*   __restrict__ steps_p,
                  const float* __restrict__ length_p,
                  const float* __restrict__ maxf_p,
                  float* __restrict__ out,
                  int L)
{
    __shared__ float rr[RRSZ + 1];                    // Raman LUT (setup only)
    __shared__ float ff[NF];                          // frequencies (setup only)
    // Y-rows (bf16): rows 0..3 = buf0 modes 0..3; rows 4..7 = buf1 modes 0..3.
    // (r9's zero row is gone — zero A-fragments live in registers now.)
    __shared__ __align__(16) unsigned short Arows[8 * AROW];

    const int t    = threadIdx.x;
    const int b    = blockIdx.x;
    const int lane = t & 63;
    const int w    = t >> 6;        // wave id 0..6 == owned freq tile (MFMA N-tile)
    const int g    = lane >> 4;     // lane-group 0..3 (K-slice for frags; C-row group)
    const int c    = lane & 15;     // frag row/col index
    const int f    = 16 * w + c;    // global frequency owned by this lane (state on g==1)
    const bool fval = (f < NF);

    // ---- stage LUT + frequencies; zero Y-rows (K-pad cols >= NF stay 0 forever) ----
    for (int k = t; k < L && k <= RRSZ; k += NT) rr[k] = raman[k];
    for (int k = t; k < 8 * AROW; k += NT) Arows[k] = 0;
    if (t < NF) ff[t] = (t < NP) ? (C0f / x[b * 20 + t]) : sig_freq[t - NP];
    __syncthreads();

    const float maxf  = maxf_p[0];
    const float scale = (float)(L - 1) / maxf;

    auto gain_of = [&](float fi, float fj) -> float {
        float fd  = fj - fi;                          // f_j - f_i
        float pos = fabsf(fd) * scale;
        int idx = (int)pos;                           // pos >= 0: trunc == floor
        if (idx > L - 2) idx = L - 2;
        float ww = pos - (float)idx;
        float gg = rr[idx] * (1.0f - ww) + rr[idx + 1] * ww;
        gg = (fd < 0.0f) ? -gg : gg;                  // antisymmetric
        return gg * fmaxf(1.0f, fi / fj);             // photon-number scaling
    };

    // ---- gain fragments (HW-verified r5-r9 build), used as the B operand:
    // per-lane value = gain[16w+c][32kt+8g+jj] == B[k=32kt+8g+jj][n=c] of gain^T ----
    short8 Gf[4];
    {
#pragma unroll
        for (int kt = 0; kt < 4; ++kt) {
#pragma unroll
            for (int jj = 0; jj < 8; ++jj) {
                const int j = 32 * kt + 8 * g + jj;
                float gv = 0.0f;
                if (fval && j < NF) gv = gain_of(ff[f], ff[j]);
                unsigned int gb = __float_as_uint(gv);
                unsigned int rb = (gb + 0x7FFFu + ((gb >> 16) & 1u)) >> 16;  // RTN-even
                Gf[kt][jj] = (short)rb;
            }
        }
    }

    // ---- full 4x4 overlap matrix per lane (uniform) ----
    float O[MD][MD];
#pragma unroll
    for (int m = 0; m < MD; ++m)
#pragma unroll
        for (int n = 0; n < MD; ++n) O[m][n] = overlap[m * MD + n];

    // ---- state: lane owns modes 0..3 of freq f (valid on g==1; others shadow) ----
    float P[4] = {0, 0, 0, 0}, lossv[4] = {0, 0, 0, 0};
    if (fval) {
        if (f < NP) {
            float wl = x[b * 20 + f] * 1e9f;
            float lv = (loss_coef[2] + loss_coef[1] * wl
                        + loss_coef[0] * wl * wl) * ALPHA_LINf;
#pragma unroll
            for (int r = 0; r < 4; ++r) { lossv[r] = lv; P[r] = x[b * 20 + NP + 4 * f + r]; }
        } else {
            const float4 lo = *(const float4*)&sig_loss[4 * f - NP * MD];
            const float4 pw = *(const float4*)&sig_pow[4 * f - NP * MD];
            lossv[0] = lo.x; lossv[1] = lo.y; lossv[2] = lo.z; lossv[3] = lo.w;
            P[0] = pw.x; P[1] = pw.y; P[2] = pw.z; P[3] = pw.w;
        }
    }

    // Only lanes with c in [4,8) carry live A rows; everyone else keeps zeros in regs.
    const bool yrow = (c >= 4 && c < 8);
    const unsigned short* pAy0 = Arows + ((c - 4) & 3) * AROW + 8 * g;
    const unsigned short* pAy1 = pAy0 + 4 * AROW;
    const bool writer = (g == 1) && fval;

    // persistent A-fragments: zero once; masked reads refresh only yrow lanes
    short8 Af0 = {0,0,0,0,0,0,0,0}, Af1 = Af0, Af2 = Af0, Af3 = Af0;

    const int   nstep = steps_p[0] - 1;
    const float h  = length_p[0] / (float)(steps_p[0] - 1);
    const float hh = 0.5f * h;
    const float h6 = h / 6.0f;

    // one ODE eval: Y = O*Xs (lane-local), RTN-pack Y->mode-rows (b16 scatter),
    // barrier, MASKED ds_read_b128 A-frags (yrow lanes only), 2x2 MFMA
    // (R lands in C-rows 4..7 = g==1 lanes), k = (R - loss)*Xs.
    auto ode_eval = [&](const float (&Xs)[4], int buf, float (&kk)[4]) {
        float Y[4];
#pragma unroll
        for (int m = 0; m < MD; ++m)
            Y[m] = O[m][0] * Xs[0] + O[m][1] * Xs[1] + O[m][2] * Xs[2] + O[m][3] * Xs[3];
        if (writer) {
            unsigned short* wbase = Arows + 4 * buf * AROW + f;
#pragma unroll
            for (int r = 0; r < 4; ++r)
                wbase[r * AROW] = (unsigned short)((__float_as_uint(Y[r]) + 0x8000u) >> 16);
        }
        __syncthreads();
        if (yrow) {
            const unsigned short* pA = buf ? pAy1 : pAy0;
            Af0 = *(const short8*)(pA);
            Af1 = *(const short8*)(pA + 32);
            Af2 = *(const short8*)(pA + 64);
            Af3 = *(const short8*)(pA + 96);
        }
        float4v a01 = {0, 0, 0, 0}, a23 = {0, 0, 0, 0};
        a01 = __builtin_amdgcn_mfma_f32_16x16x32_bf16(Af0, Gf[0], a01, 0, 0, 0);
        a01 = __builtin_amdgcn_mfma_f32_16x16x32_bf16(Af1, Gf[1], a01, 0, 0, 0);
        a23 = __builtin_amdgcn_mfma_f32_16x16x32_bf16(Af2, Gf[2], a23, 0, 0, 0);
        a23 = __builtin_amdgcn_mfma_f32_16x16x32_bf16(Af3, Gf[3], a23, 0, 0, 0);
#pragma unroll
        for (int r = 0; r < 4; ++r)
            kk[r] = ((a01[r] + a23[r]) - lossv[r]) * Xs[r];   // R valid on g==1 lanes
    };

    for (int s = 0; s < nstep; ++s) {
        float k1[4], kc[4], Xs[4], ka[4];
        ode_eval(P, 0, k1);
#pragma unroll
        for (int r = 0; r < 4; ++r) { ka[r] = k1[r]; Xs[r] = P[r] + hh * k1[r]; }
        ode_eval(Xs, 1, kc);
#pragma unroll
        for (int r = 0; r < 4; ++r) { ka[r] += 2.0f * kc[r]; Xs[r] = P[r] + hh * kc[r]; }
        ode_eval(Xs, 0, kc);
#pragma unroll
        for (int r = 0; r < 4; ++r) { ka[r] += 2.0f * kc[r]; Xs[r] = P[r] + h * kc[r]; }
        ode_eval(Xs, 1, kc);
#pragma unroll
        for (int r = 0; r < 4; ++r) P[r] += h6 * (ka[r] + kc[r]);
    }

    // ---- write signal spectrum (B, NC, MD): freq f -> out[4f-16 .. 4f-13] ----
    if (writer && f >= NP) {
        float4 o4 = make_float4(P[0], P[1], P[2], P[3]);
        *(float4*)&out[b * (NC * MD) + 4 * f - NP * MD] = o4;
    }
}

extern "C" void kernel_launch(void* const* d_in, const int* in_sizes, int n_in,
                              void* d_out, int out_size, void* d_ws, size_t ws_size,
                              hipStream_t stream) {
    const float* x   = (const float*)d_in[0];
    const float* sf  = (const float*)d_in[1];
    const float* sp  = (const float*)d_in[2];
    const float* sl  = (const float*)d_in[3];
    const float* lc  = (const float*)d_in[4];
    const float* ov  = (const float*)d_in[5];
    const float* rrp = (const float*)d_in[6];
    const int*   stp = (const int*)d_in[10];
    const float* len = (const float*)d_in[11];
    const float* mxf = (const float*)d_in[12];

    const int B = in_sizes[0] / (NP * (1 + MD));   // 512
    const int L = in_sizes[6];                     // 801

    raman_kernel<<<dim3(B), dim3(NT), 0, stream>>>(
        x, sf, sp, sl, lc, ov, rrp, stp, len, mxf, (float*)d_out, L);
}

// Round 11
// 225.709 us; speedup vs baseline: 1.2868x; 1.0270x over previous
//
#include <hip/hip_runtime.h>
#include <math.h>

#define C0f        299792458.0f
#define ALPHA_LINf 2.3025850929940458e-4f   // 1e-3 * ln(10)/10

#define NP   4
#define MD   4
#define NC   100
#define NF   104          // NP + NC
#define NT   448          // 7 waves; wave w owns N-tile w (freqs 16w..16w+15); 2 blocks/CU
#define RRSZ 801
#define AROW 136          // ushorts per Y-row (272 B; 4-dword bank stagger)

typedef __attribute__((ext_vector_type(8))) short  short8;   // bf16 MFMA A/B frag
typedef __attribute__((ext_vector_type(4))) float  float4v;  // MFMA C/D frag
typedef __attribute__((ext_vector_type(2))) float  float2v;  // v_pk_* pair

__device__ __forceinline__ float2v fma2(float2v a, float2v b, float2v c) {
    return __builtin_elementwise_fma(a, b, c);
}

__global__ __launch_bounds__(NT, 4)   // 4 waves/EU -> VGPR cap 128
void raman_kernel(const float* __restrict__ x,
                  const float* __restrict__ sig_freq,
                  const float* __restrict__ sig_pow,
                  const float* __restrict__ sig_loss,
                  const float* __restrict__ loss_coef,
                  const float* __restrict__ overlap,
                  const float* __restrict__ raman,
                  const int*   __restrict__ steps_p,
                  const float* __restrict__ length_p,
                  const float* __restrict__ maxf_p,
                  float* __restrict__ out,
                  int L)
{
    __shared__ float rr[RRSZ + 1];                    // Raman LUT (setup only)
    __shared__ float ff[NF];                          // frequencies (setup only)
    // Y-rows (bf16): rows 0..3 = buf0 modes, rows 4..7 = buf1 modes.
    __shared__ __align__(16) unsigned short Arows[8 * AROW];

    const int t    = threadIdx.x;
    const int b    = blockIdx.x;
    const int lane = t & 63;
    const int w    = t >> 6;        // wave id 0..6 == owned freq tile (MFMA N-tile)
    const int g    = lane >> 4;     // lane-group 0..3 (K-slice; C-row group)
    const int c    = lane & 15;     // frag row/col index
    const int f    = 16 * w + c;    // owned frequency (state lives on g==1 lanes)
    const bool fval = (f < NF);

    // ---- stage LUT + frequencies; zero Y-rows (K-pad stays 0 forever) ----
    for (int k = t; k < L && k <= RRSZ; k += NT) rr[k] = raman[k];
    for (int k = t; k < 8 * AROW; k += NT) Arows[k] = 0;
    if (t < NF) ff[t] = (t < NP) ? (C0f / x[b * 20 + t]) : sig_freq[t - NP];
    __syncthreads();

    const float maxf  = maxf_p[0];
    const float scale = (float)(L - 1) / maxf;

    auto gain_of = [&](float fi, float fj) -> float {
        float fd  = fj - fi;
        float pos = fabsf(fd) * scale;
        int idx = (int)pos;
        if (idx > L - 2) idx = L - 2;
        float ww = pos - (float)idx;
        float gg = rr[idx] * (1.0f - ww) + rr[idx + 1] * ww;
        gg = (fd < 0.0f) ? -gg : gg;
        return gg * fmaxf(1.0f, fi / fj);
    };

    // ---- gain fragments (HW-verified r5-r10), used as B operand (== gain^T) ----
    short8 Gf[4];
    {
#pragma unroll
        for (int kt = 0; kt < 4; ++kt) {
#pragma unroll
            for (int jj = 0; jj < 8; ++jj) {
                const int j = 32 * kt + 8 * g + jj;
                float gv = 0.0f;
                if (fval && j < NF) gv = gain_of(ff[f], ff[j]);
                unsigned int gb = __float_as_uint(gv);
                unsigned int rb = (gb + 0x7FFFu + ((gb >> 16) & 1u)) >> 16;  // RTN-even
                Gf[kt][jj] = (short)rb;
            }
        }
    }

    // ---- overlap columns as pk pairs: Oc01[c] = {O[0][c],O[1][c]}, Oc23[c] = {O[2][c],O[3][c]} ----
    float2v Oc01[4], Oc23[4];
#pragma unroll
    for (int cc = 0; cc < 4; ++cc) {
        Oc01[cc] = float2v{overlap[0 * MD + cc], overlap[1 * MD + cc]};
        Oc23[cc] = float2v{overlap[2 * MD + cc], overlap[3 * MD + cc]};
    }

    // ---- state (modes of freq f; valid on g==1 lanes) as pk pairs ----
    float2v P01 = {0, 0}, P23 = {0, 0}, loss01 = {0, 0}, loss23 = {0, 0};
    if (fval) {
        if (f < NP) {
            float wl = x[b * 20 + f] * 1e9f;
            float lv = (loss_coef[2] + loss_coef[1] * wl
                        + loss_coef[0] * wl * wl) * ALPHA_LINf;
            loss01 = float2v{lv, lv}; loss23 = float2v{lv, lv};
            P01 = float2v{x[b * 20 + NP + 4 * f + 0], x[b * 20 + NP + 4 * f + 1]};
            P23 = float2v{x[b * 20 + NP + 4 * f + 2], x[b * 20 + NP + 4 * f + 3]};
        } else {
            const float4 lo = *(const float4*)&sig_loss[4 * f - NP * MD];
            const float4 pw = *(const float4*)&sig_pow[4 * f - NP * MD];
            loss01 = float2v{lo.x, lo.y}; loss23 = float2v{lo.z, lo.w};
            P01 = float2v{pw.x, pw.y};    P23 = float2v{pw.z, pw.w};
        }
    }

    const bool yrow = (c >= 4 && c < 8);
    const unsigned short* pAy0 = Arows + ((c - 4) & 3) * AROW + 8 * g;
    const unsigned short* pAy1 = pAy0 + 4 * AROW;
    const bool writer = (g == 1) && fval;

    // persistent A-fragments: zero once; masked reads refresh only yrow lanes
    short8 Af0 = {0,0,0,0,0,0,0,0}, Af1 = Af0, Af2 = Af0, Af3 = Af0;
    const float4v ZEROv = {0.0f, 0.0f, 0.0f, 0.0f};   // persistent zero C operand

    const int   nstep = steps_p[0] - 1;
    const float h  = length_p[0] / (float)(steps_p[0] - 1);
    const float2v hhv = {0.5f * h, 0.5f * h};
    const float2v hv  = {h, h};
    const float2v h6v = {h / 6.0f, h / 6.0f};
    const float2v twov = {2.0f, 2.0f};

    // one ODE eval (pk-packed glue)
    auto ode_eval = [&](float2v Xs01, float2v Xs23, int buf,
                        float2v& k01, float2v& k23) {
        // Y = O * Xs  (pk_fma: 8 instrs)
        float2v xs0 = {Xs01[0], Xs01[0]}, xs1 = {Xs01[1], Xs01[1]};
        float2v xs2 = {Xs23[0], Xs23[0]}, xs3 = {Xs23[1], Xs23[1]};
        float2v Y01 = fma2(Oc01[0], xs0, fma2(Oc01[1], xs1, fma2(Oc01[2], xs2, Oc01[3] * xs3)));
        float2v Y23 = fma2(Oc23[0], xs0, fma2(Oc23[1], xs1, fma2(Oc23[2], xs2, Oc23[3] * xs3)));
        if (writer) {
            unsigned short* wbase = Arows + 4 * buf * AROW + f;
            wbase[0 * AROW] = (unsigned short)((__float_as_uint(Y01[0]) + 0x8000u) >> 16);
            wbase[1 * AROW] = (unsigned short)((__float_as_uint(Y01[1]) + 0x8000u) >> 16);
            wbase[2 * AROW] = (unsigned short)((__float_as_uint(Y23[0]) + 0x8000u) >> 16);
            wbase[3 * AROW] = (unsigned short)((__float_as_uint(Y23[1]) + 0x8000u) >> 16);
        }
        __syncthreads();
        if (yrow) {
            const unsigned short* pA = buf ? pAy1 : pAy0;
            Af0 = *(const short8*)(pA);
            Af1 = *(const short8*)(pA + 32);
            Af2 = *(const short8*)(pA + 64);
            Af3 = *(const short8*)(pA + 96);
        }
        float4v a01 = __builtin_amdgcn_mfma_f32_16x16x32_bf16(Af0, Gf[0], ZEROv, 0, 0, 0);
        a01         = __builtin_amdgcn_mfma_f32_16x16x32_bf16(Af1, Gf[1], a01,   0, 0, 0);
        float4v a23 = __builtin_amdgcn_mfma_f32_16x16x32_bf16(Af2, Gf[2], ZEROv, 0, 0, 0);
        a23         = __builtin_amdgcn_mfma_f32_16x16x32_bf16(Af3, Gf[3], a23,   0, 0, 0);
        // R pairs + k  (pk: ~6 instrs)
        float2v R01 = __builtin_shufflevector(a01, a01, 0, 1)
                    + __builtin_shufflevector(a23, a23, 0, 1);
        float2v R23 = __builtin_shufflevector(a01, a01, 2, 3)
                    + __builtin_shufflevector(a23, a23, 2, 3);
        k01 = (R01 - loss01) * Xs01;
        k23 = (R23 - loss23) * Xs23;
    };

    for (int s = 0; s < nstep; ++s) {
        float2v k1a, k1b, kca, kcb, Xa, Xb, kaa, kab;
        ode_eval(P01, P23, 0, k1a, k1b);
        kaa = k1a; kab = k1b;
        Xa = fma2(hhv, k1a, P01); Xb = fma2(hhv, k1b, P23);
        ode_eval(Xa, Xb, 1, kca, kcb);
        kaa = fma2(twov, kca, kaa); kab = fma2(twov, kcb, kab);
        Xa = fma2(hhv, kca, P01); Xb = fma2(hhv, kcb, P23);
        ode_eval(Xa, Xb, 0, kca, kcb);
        kaa = fma2(twov, kca, kaa); kab = fma2(twov, kcb, kab);
        Xa = fma2(hv, kca, P01); Xb = fma2(hv, kcb, P23);
        ode_eval(Xa, Xb, 1, kca, kcb);
        P01 = fma2(h6v, kaa + kca, P01);
        P23 = fma2(h6v, kab + kcb, P23);
    }

    // ---- write signal spectrum (B, NC, MD): freq f -> out[4f-16 .. 4f-13] ----
    if (writer && f >= NP) {
        float4 o4 = make_float4(P01[0], P01[1], P23[0], P23[1]);
        *(float4*)&out[b * (NC * MD) + 4 * f - NP * MD] = o4;
    }
}

extern "C" void kernel_launch(void* const* d_in, const int* in_sizes, int n_in,
                              void* d_out, int out_size, void* d_ws, size_t ws_size,
                              hipStream_t stream) {
    const float* x   = (const float*)d_in[0];
    const float* sf  = (const float*)d_in[1];
    const float* sp  = (const float*)d_in[2];
    const float* sl  = (const float*)d_in[3];
    const float* lc  = (const float*)d_in[4];
    const float* ov  = (const float*)d_in[5];
    const float* rrp = (const float*)d_in[6];
    const int*   stp = (const int*)d_in[10];
    const float* len = (const float*)d_in[11];
    const float* mxf = (const float*)d_in[12];

    const int B = in_sizes[0] / (NP * (1 + MD));   // 512
    const int L = in_sizes[6];                     // 801

    raman_kernel<<<dim3(B), dim3(NT), 0, stream>>>(
        x, sf, sp, sl, lc, ov, rrp, stp, len, mxf, (float*)d_out, L);
}